// Round 7
// baseline (856.334 us; speedup 1.0000x reference)
//
#include <hip/hip_runtime.h>

// SelfAttnPool: B=32, T=4096, F=512, U=512 (fp32 in/out)
//   scores[b,t] = tanh(x[b,t,:]@W + b) @ V ; a = softmax_T(scores)
//   out[b,f] = sum_t a[b,t]*x[b,t,f]
//
// R6: B moved off the VMEM pipe. Evidence R2/R4/R5: MfmaUtil ~= 60 B/cyc/CU
// divided by VMEM demand per MFMA-cycle -> VMEM-return-BW bound. Fix: stage
// B hi/lo slices (32 KB per k=16) into LDS via async global_load_lds,
// double-buffered, 1 barrier per k-step; waves read B as ds_read_b128.
// Block 512 thr = 8 waves (2 row-groups x 4 col-quarters), tile 128r x 512c,
// wave 64r x 128c (acc 128 AGPR). Flash chunk-softmax epilogue kept.
// 3-term bf16 split (hh+lh+hl) on mfma 32x32x16 for fp32-grade scores.

#define XT 4096
#define XF 512
#define XU 512
#define CPB 32               // 128-row chunks per batch

typedef __attribute__((ext_vector_type(8))) short short8;
typedef __attribute__((ext_vector_type(16))) float f32x16;

__device__ inline unsigned fbits(float x) { return __builtin_bit_cast(unsigned, x); }

__device__ inline void cvt_hilo(float x, unsigned short &h, unsigned short &l) {
  unsigned u = fbits(x);
  h = (unsigned short)(u >> 16);                       // truncated bf16 hi
  float hf = __builtin_bit_cast(float, u & 0xFFFF0000u);
  float lo = x - hf;                                   // exact residual
  l = (unsigned short)(fbits(lo) >> 16);
}

__device__ inline void async_ld16(const void *g, void *l) {
  __builtin_amdgcn_global_load_lds(
      (const __attribute__((address_space(1))) unsigned int *)g,
      (__attribute__((address_space(3))) unsigned int *)l, 16, 0, 0);
}

__device__ inline float tanh_fast(float z) {
  float e = __expf(2.0f * z);
  return 1.0f - 2.0f * __builtin_amdgcn_rcpf(e + 1.0f);
}

// ---- W pre-conversion: fp32 [512 k][512 n] -> bf16 hi/lo, fragment-ready:
// whi/wlo: [slice s(32)][chunk16B: t(16)*64 + g(2)*32 + l(32)][j(8)]
// element = W[k = s*16 + g*8 + j][n = t*32 + l];  slice = 8192 shorts (16 KB)
__global__ void wconv_kernel(const float *__restrict__ W,
                             unsigned short *__restrict__ whi,
                             unsigned short *__restrict__ wlo) {
  int t2 = blockIdx.x * 256 + threadIdx.x;  // 32768 threads
  int l = t2 & 31;
  int g = (t2 >> 5) & 1;
  int t = (t2 >> 6) & 15;
  int s = t2 >> 10;
  short8 hv, lv;
#pragma unroll
  for (int j = 0; j < 8; ++j) {
    unsigned short h, lo;
    cvt_hilo(W[(size_t)(s * 16 + g * 8 + j) * XU + t * 32 + l], h, lo);
    hv[j] = (short)h;
    lv[j] = (short)lo;
  }
  size_t off = (size_t)s * 8192 + t * 512 + g * 256 + l * 8;
  *(short8 *)(whi + off) = hv;
  *(short8 *)(wlo + off) = lv;
}

#define MFMA(a, b, c) __builtin_amdgcn_mfma_f32_32x32x16_bf16(a, b, c, 0, 0, 0)

// ---- fused GEMM + tanh + (.@V) + chunk softmax + weighted pooling
__global__ __launch_bounds__(512, 2)
void gemm_scores_kernel(const float *__restrict__ x,
                        const unsigned short *__restrict__ whi,
                        const unsigned short *__restrict__ wlo,
                        const float *__restrict__ bias,
                        const float *__restrict__ V,
                        float *__restrict__ partial,
                        float *__restrict__ pstats) {
  // 2 x 32 KB B double-buffer: [buf][hi 8192 | lo 8192] shorts
  __shared__ unsigned short bsm[32768];
  __shared__ float scb[512];   // per-wave-quarter partial scores
  __shared__ float sarr[128];
  __shared__ float warr[128];  // chunk-local softmax weights
  __shared__ float red[1536];  // pooling cross-rowgroup reduction

  const int tid = threadIdx.x;
  const int lane = tid & 63;
  const int wave = tid >> 6;
  const int wr = wave >> 2;   // row half (64 rows)
  const int wc = wave & 3;    // col quarter (128 cols)
  const int l31 = lane & 31;
  const int half = lane >> 5;
  const size_t rowbase = (size_t)blockIdx.x * 128;

  f32x16 acc[2][4];
#pragma unroll
  for (int a = 0; a < 2; ++a)
#pragma unroll
    for (int c = 0; c < 4; ++c)
#pragma unroll
      for (int r = 0; r < 16; ++r) acc[a][c][r] = 0.f;

  // A: row = rowbase + wr*64 + rf*32 + l31 ; k = s*16 + half*8 + j
  const float *xr0 = x + (rowbase + wr * 64 + l31) * XF + half * 8;
  const float *xr1 = xr0 + 32 * XF;
  // B fragment base inside an LDS buffer (shorts): (wc*4+cf)*512 + half*256 + l31*8
  const int bfrag = (wc * 4) * 512 + half * 256 + l31 * 8;

  // staging: 32 chunks of 1 KB per slice (16 hi + 16 lo); wave stages 4.
  const int c0 = wave * 4;

  // prologue: stage slice 0 into buf 0; load A(0)
#pragma unroll
  for (int i = 0; i < 4; ++i) {
    int c = c0 + i;
    const unsigned short *src =
        (c < 16 ? whi + c * 512 : wlo + (c - 16) * 512) + lane * 8;
    async_ld16(src, bsm + (c < 16 ? c * 512 : 8192 + (c - 16) * 512) + lane * 8);
  }
  float4 raw[2][4];
  raw[0][0] = *(const float4 *)(xr0);
  raw[0][1] = *(const float4 *)(xr0 + 4);
  raw[0][2] = *(const float4 *)(xr1);
  raw[0][3] = *(const float4 *)(xr1 + 4);

#pragma unroll 1
  for (int s = 0; s < 32; ++s) {
    const int cur = s & 1, nxt = cur ^ 1;
    __syncthreads();  // slice s staged into buf cur; raw[cur] landed

    if (s < 31) {
      const unsigned short *hsl = whi + (size_t)(s + 1) * 8192;
      const unsigned short *lsl = wlo + (size_t)(s + 1) * 8192;
#pragma unroll
      for (int i = 0; i < 4; ++i) {
        int c = c0 + i;
        const unsigned short *src =
            (c < 16 ? hsl + c * 512 : lsl + (c - 16) * 512) + lane * 8;
        async_ld16(src, bsm + nxt * 16384 +
                            (c < 16 ? c * 512 : 8192 + (c - 16) * 512) +
                            lane * 8);
      }
      raw[nxt][0] = *(const float4 *)(xr0 + (s + 1) * 16);
      raw[nxt][1] = *(const float4 *)(xr0 + (s + 1) * 16 + 4);
      raw[nxt][2] = *(const float4 *)(xr1 + (s + 1) * 16);
      raw[nxt][3] = *(const float4 *)(xr1 + (s + 1) * 16 + 4);
    }

    short8 ah0, al0, ah1, al1;
    {
      float v0[8] = {raw[cur][0].x, raw[cur][0].y, raw[cur][0].z, raw[cur][0].w,
                     raw[cur][1].x, raw[cur][1].y, raw[cur][1].z, raw[cur][1].w};
      float v1[8] = {raw[cur][2].x, raw[cur][2].y, raw[cur][2].z, raw[cur][2].w,
                     raw[cur][3].x, raw[cur][3].y, raw[cur][3].z, raw[cur][3].w};
#pragma unroll
      for (int j = 0; j < 8; ++j) {
        unsigned short h, lo;
        cvt_hilo(v0[j], h, lo);
        ah0[j] = (short)h; al0[j] = (short)lo;
        cvt_hilo(v1[j], h, lo);
        ah1[j] = (short)h; al1[j] = (short)lo;
      }
    }

    const unsigned short *bb = bsm + cur * 16384 + bfrag;
#pragma unroll
    for (int cf = 0; cf < 4; ++cf) {
      short8 bh = *(const short8 *)(bb + cf * 512);
      short8 bl = *(const short8 *)(bb + cf * 512 + 8192);
      acc[0][cf] = MFMA(ah0, bh, acc[0][cf]);
      acc[1][cf] = MFMA(ah1, bh, acc[1][cf]);
      acc[0][cf] = MFMA(al0, bh, acc[0][cf]);
      acc[1][cf] = MFMA(al1, bh, acc[1][cf]);
      acc[0][cf] = MFMA(ah0, bl, acc[0][cf]);
      acc[1][cf] = MFMA(ah1, bl, acc[1][cf]);
    }
  }

  // ---- score epilogue: sc[row] = sum_n tanh(acc + b[n]) * V[n]
  // C/D 32x32: col n = l31 (+32*cf+128*wc); row = (r&3)+8*(r>>2)+4*half (+32*rf+64*wr)
  float sc[2][16];
#pragma unroll
  for (int rf = 0; rf < 2; ++rf)
#pragma unroll
    for (int r = 0; r < 16; ++r) sc[rf][r] = 0.f;

#pragma unroll
  for (int cf = 0; cf < 4; ++cf) {
    int n = wc * 128 + cf * 32 + l31;
    float vv = V[n];
    float bb2 = bias[n];
#pragma unroll
    for (int rf = 0; rf < 2; ++rf)
#pragma unroll
      for (int r = 0; r < 16; ++r)
        sc[rf][r] += tanh_fast(acc[rf][cf][r] + bb2) * vv;
  }
#pragma unroll
  for (int m = 1; m <= 16; m <<= 1) {
#pragma unroll
    for (int rf = 0; rf < 2; ++rf)
#pragma unroll
      for (int r = 0; r < 16; ++r)
        sc[rf][r] += __shfl_xor(sc[rf][r], m, 64);
  }
  __syncthreads();  // staging of (dead) slice 31+1 never issued; protect scb
  if (l31 == 0) {
#pragma unroll
    for (int rf = 0; rf < 2; ++rf)
#pragma unroll
      for (int r = 0; r < 16; ++r) {
        int row = wr * 64 + rf * 32 + (r & 3) + 8 * (r >> 2) + 4 * half;
        scb[wc * 128 + row] = sc[rf][r];
      }
  }
  __syncthreads();

  // ---- chunk-local softmax: s_t -> m_c, w_t = e^{s_t - m_c}
  if (tid < 128)
    sarr[tid] = scb[tid] + scb[128 + tid] + scb[256 + tid] + scb[384 + tid];
  __syncthreads();
  float mloc = -1e30f;
#pragma unroll 8
  for (int i = 0; i < 128; ++i) mloc = fmaxf(mloc, sarr[i]);
  if (tid < 128) warr[tid] = __expf(sarr[tid] - mloc);
  __syncthreads();

  // ---- weighted pooling over own (L2-hot) tile: 4 row-groups x 128 col4s
  const int rg = tid >> 7;   // 0..3 -> rows rg*32..+32
  const int c4 = tid & 127;  // float4 column
  const float *xp = x + rowbase * XF;
  float4 pa = {0.f, 0.f, 0.f, 0.f};
#pragma unroll 8
  for (int i = 0; i < 32; ++i) {
    int r = rg * 32 + i;
    float4 v = *(const float4 *)(xp + (size_t)r * XF + c4 * 4);
    float wv = warr[r];
    pa.x += wv * v.x;
    pa.y += wv * v.y;
    pa.z += wv * v.z;
    pa.w += wv * v.w;
  }
  if (rg > 0) {
    float *rp = red + (rg - 1) * 512 + c4 * 4;
    rp[0] = pa.x; rp[1] = pa.y; rp[2] = pa.z; rp[3] = pa.w;
  }
  __syncthreads();
  if (rg == 0) {
    const float *r0 = red + c4 * 4;
    float4 o;
    o.x = pa.x + r0[0] + r0[512] + r0[1024];
    o.y = pa.y + r0[1] + r0[513] + r0[1025];
    o.z = pa.z + r0[2] + r0[514] + r0[1026];
    o.w = pa.w + r0[3] + r0[515] + r0[1027];
    *(float4 *)(partial + (size_t)blockIdx.x * 512 + c4 * 4) = o;
  }
  if (tid == 0) {
    float l = 0.f;
#pragma unroll 8
    for (int i = 0; i < 128; ++i) l += warr[i];
    pstats[blockIdx.x * 2] = mloc;
    pstats[blockIdx.x * 2 + 1] = l;
  }
}

// ---- combine: out[b,f] = sum_c e^{m_c-M} partial[c][f] / (sum_c e^{m_c-M} l_c)
__global__ __launch_bounds__(512)
void combine_kernel(const float *__restrict__ partial,
                    const float *__restrict__ pstats,
                    float *__restrict__ out) {
  int b = blockIdx.x;
  int f = threadIdx.x;
  __shared__ float ml[CPB], ll[CPB];
  if (f < CPB) {
    ml[f] = pstats[(b * CPB + f) * 2];
    ll[f] = pstats[(b * CPB + f) * 2 + 1];
  }
  __syncthreads();
  float M = -1e30f;
#pragma unroll
  for (int c = 0; c < CPB; ++c) M = fmaxf(M, ml[c]);
  float L = 0.f;
  float acc = 0.f;
#pragma unroll
  for (int c = 0; c < CPB; ++c) {
    float e = __expf(ml[c] - M);
    L += e * ll[c];
    acc += e * partial[(size_t)(b * CPB + c) * 512 + f];
  }
  out[b * XF + f] = acc / L;
}

extern "C" void kernel_launch(void *const *d_in, const int *in_sizes, int n_in,
                              void *d_out, int out_size, void *d_ws,
                              size_t ws_size, hipStream_t stream) {
  const float *x = (const float *)d_in[0];
  const float *W = (const float *)d_in[1];
  const float *bias = (const float *)d_in[2];
  const float *V = (const float *)d_in[3];
  float *out = (float *)d_out;

  // workspace: whi 512KB | wlo 512KB | partial 2MB | pstats 8KB
  unsigned short *whi = (unsigned short *)d_ws;
  unsigned short *wlo = whi + 262144;
  float *partial = (float *)((char *)d_ws + 1048576);
  float *pstats = (float *)((char *)d_ws + 1048576 + 2097152);

  wconv_kernel<<<128, 256, 0, stream>>>(W, whi, wlo);
  gemm_scores_kernel<<<1024, 512, 0, stream>>>(x, whi, wlo, bias, V, partial,
                                               pstats);
  combine_kernel<<<32, 512, 0, stream>>>(partial, pstats, out);
}